// Round 8
// baseline (342.248 us; speedup 1.0000x reference)
//
#include <hip/hip_runtime.h>
#include <hip/hip_bf16.h>
#include <math.h>
#include <stdint.h>

// ---------------------------------------------------------------------------
// Transformer block: x + attn(rms(x,g1)) -> x1 ; x1 + ffn(rms(x1,g2))
// B=2 T=2048 D=1024 H=16 Dh=64 FF=4096. All GEMMs bf16 MFMA 16x16x32.
// R16: R13 base (session best 323.2us) + non-GEMM time buyback:
//  (1) QKV gemm256 MODE 3 writes the V-part DIRECTLY transposed into VTg
//      (V cols were only ever read by transpose_v) -> transpose_v deleted
//      (-1 dispatch, -16MB traffic).
//  (2) R14's prep_kernel fusion (3 weight transposes + rmsnorm1 in one
//      dispatch; ran correct in R14, whose regression tracked the reverted
//      MT=2 GEMM change). 10 dispatches -> 7.
//  GEMM lessons final: counted-vmcnt always defeated (R9-R11); MT=2
//  occupancy-first loses to B-traffic (R14); dbuf on small tile loses
//  occupancy/L2 (R15). gemm256 2-phase 256^2 (R13) kept for QKV/FFN1;
//  legacy 2-barrier kept for Wo/FFN2.
// LDS tiles use XOR-swizzled 16B chunks (chunk j of row r lives at j^(r&7));
// rocprof shows SQ_LDS_BANK_CONFLICT == 0 for this scheme.
// ---------------------------------------------------------------------------

typedef __bf16 v8bf  __attribute__((ext_vector_type(8)));
typedef float  v4f   __attribute__((ext_vector_type(4)));

#define T_SEQ 2048
#define EXP2F(x) __builtin_amdgcn_exp2f(x)  // v_exp_f32 (2^x)

// swizzled fragment read: row R, k-elem offset ko (multiple of 8)
#define FRAG(base, R, ko) \
  (*(const v8bf*)((base) + (R) * 64 + (((((ko) >> 3) ^ ((R) & 7))) << 3)))

__device__ __forceinline__ void async_ld16(const void* g, void* l) {
  // global -> LDS direct, 16B/lane. LDS dest is wave-uniform base + lane*16.
  __builtin_amdgcn_global_load_lds(
      (const __attribute__((address_space(1))) uint32_t*)g,
      (__attribute__((address_space(3))) uint32_t*)l, 16, 0, 0);
}

// ---------------- prep: 6 weight transposes + rmsnorm1, one dispatch -------
// grid 16384 x (32,8):
//  [    0, 4096): Wq/Wk/Wv/Wo fp32->bf16 transpose -> WqkvT (z = id>>10)
//  [ 4096, 8192): W1  (K=1024,N=4096,ldo=1024) -> W1T
//  [ 8192,12288): W2  (K=4096,N=1024,ldo=4096) -> W2T
//  [12288,16384): rmsnorm1 row (id-12288): xn = rms(x,g1) bf16
__global__ __launch_bounds__(256) void prep_kernel(
    const float* __restrict__ Wq, const float* __restrict__ Wk,
    const float* __restrict__ Wv, const float* __restrict__ Wo,
    const float* __restrict__ W1, const float* __restrict__ W2,
    __hip_bfloat16* __restrict__ WqkvT,
    __hip_bfloat16* __restrict__ W1T,
    __hip_bfloat16* __restrict__ W2T,
    const float* __restrict__ x, const float* __restrict__ g1,
    __hip_bfloat16* __restrict__ xn)
{
  __shared__ float tile[32][33];
  __shared__ float red[4];
  const int id = blockIdx.x;
  const int tx = threadIdx.x, ty = threadIdx.y;  // 32 x 8

  if (id >= 12288) {  // ---- rmsnorm1
    const int row = id - 12288;
    const int t = ty * 32 + tx;
    const float4 v = ((const float4*)(x + (size_t)row * 1024))[t];
    float ss = v.x * v.x + v.y * v.y + v.z * v.z + v.w * v.w;
#pragma unroll
    for (int off = 32; off; off >>= 1) ss += __shfl_xor(ss, off, 64);
    if ((t & 63) == 0) red[t >> 6] = ss;
    __syncthreads();
    ss = red[0] + red[1] + red[2] + red[3];
    const float rs = rsqrtf(ss * (1.0f / 1024.0f) + 1e-6f);
    const float4 gv = ((const float4*)g1)[t];
    __hip_bfloat16* o = xn + (size_t)row * 1024 + t * 4;
    o[0] = __float2bfloat16(v.x * rs * gv.x);
    o[1] = __float2bfloat16(v.y * rs * gv.y);
    o[2] = __float2bfloat16(v.z * rs * gv.z);
    o[3] = __float2bfloat16(v.w * rs * gv.w);
    return;
  }

  const float* W;
  __hip_bfloat16* WT;
  int N, ldo, n0, k0;
  if (id < 4096) {           // ---- Wq/Wk/Wv/Wo (1024x1024 each)
    const int z = id >> 10, rem = id & 1023;
    W = z == 0 ? Wq : z == 1 ? Wk : z == 2 ? Wv : Wo;
    WT = WqkvT + (size_t)z * 1024 * 1024;
    N = 1024; ldo = 1024;
    n0 = (rem & 31) * 32; k0 = (rem >> 5) * 32;
  } else if (id < 8192) {    // ---- W1 (1024x4096)
    const int rem = id - 4096;
    W = W1; WT = W1T; N = 4096; ldo = 1024;
    n0 = (rem & 127) * 32; k0 = (rem >> 7) * 32;
  } else {                   // ---- W2 (4096x1024)
    const int rem = id - 8192;
    W = W2; WT = W2T; N = 1024; ldo = 4096;
    n0 = (rem & 31) * 32; k0 = (rem >> 5) * 32;
  }
#pragma unroll
  for (int i = 0; i < 32; i += 8)
    tile[ty + i][tx] = W[(size_t)(k0 + ty + i) * N + n0 + tx];
  __syncthreads();
#pragma unroll
  for (int i = 0; i < 32; i += 8)
    WT[(size_t)(n0 + ty + i) * ldo + k0 + tx] = __float2bfloat16(tile[tx][ty + i]);
}

// ---------------- RMSNorm (fp32 in -> bf16 out, optional d_out init) -------
__global__ __launch_bounds__(256) void rmsnorm_kernel(
    const float* __restrict__ x, const float* __restrict__ g,
    __hip_bfloat16* __restrict__ out,
    const float* __restrict__ bias, float* __restrict__ dinit)
{
  const int row = blockIdx.x;
  const int t = threadIdx.x;
  const float4 v = ((const float4*)(x + (size_t)row * 1024))[t];
  float ss = v.x * v.x + v.y * v.y + v.z * v.z + v.w * v.w;
#pragma unroll
  for (int off = 32; off; off >>= 1) ss += __shfl_xor(ss, off, 64);
  __shared__ float red[4];
  if ((t & 63) == 0) red[t >> 6] = ss;
  __syncthreads();
  ss = red[0] + red[1] + red[2] + red[3];
  const float rs = rsqrtf(ss * (1.0f / 1024.0f) + 1e-6f);
  const float4 gv = ((const float4*)g)[t];
  __hip_bfloat16* o = out + (size_t)row * 1024 + t * 4;
  o[0] = __float2bfloat16(v.x * rs * gv.x);
  o[1] = __float2bfloat16(v.y * rs * gv.y);
  o[2] = __float2bfloat16(v.z * rs * gv.z);
  o[3] = __float2bfloat16(v.w * rs * gv.w);
  if (dinit) {
    const float4 bv = ((const float4*)bias)[t];
    float4 d;
    d.x = v.x + bv.x; d.y = v.y + bv.y; d.z = v.z + bv.z; d.w = v.w + bv.w;
    ((float4*)(dinit + (size_t)row * 1024))[t] = d;
  }
}

// ---------------- legacy GEMM (Wo, FFN2): C = A @ BT^T (+epilogue) ---------
// MODE 1: outf = resid + C   MODE 4: atomicAdd(outf, C)
template <int MODE, int MT, int PX, int PY>
__global__ __launch_bounds__(256, 2) void gemm_bt(
    const __hip_bfloat16* __restrict__ A,
    const __hip_bfloat16* __restrict__ BT,
    const float* __restrict__ bias,
    const float* __restrict__ resid,
    __hip_bfloat16* __restrict__ outb,
    float* __restrict__ outf,
    int M, int N, int K, int Ksub)
{
  __shared__ __align__(16) __hip_bfloat16 As[32 * MT * 64];
  __shared__ __align__(16) __hip_bfloat16 Bs[128 * 64];
  const int tid = threadIdx.x;
  const int wave = tid >> 6, lane = tid & 63;
  const int quad = lane >> 4, l16 = lane & 15;

  int bx = blockIdx.x, by = blockIdx.y;
  {
    const int id = by * gridDim.x + bx;
    const int k = id & 7, s = id >> 3;
    const int pw = gridDim.x / PX, ph = gridDim.y / PY;
    bx = (k % PX) * pw + (s % pw);
    by = (k / PX) * ph + (s / pw);
  }
  const int m0 = by * (32 * MT), n0 = bx * 128;
  const size_t kb = (size_t)blockIdx.z * Ksub;
  const int wr = (wave >> 1) * (16 * MT), wc = (wave & 1) * 64;
  const int lrow = lane >> 3;
  const int scol = ((lane & 7) ^ lrow) * 8;

  v4f acc[MT][4];
#pragma unroll
  for (int i = 0; i < MT; i++)
#pragma unroll
    for (int j = 0; j < 4; j++)
#pragma unroll
      for (int c = 0; c < 4; c++) acc[i][j][c] = 0.0f;

  for (int k0 = 0; k0 < Ksub; k0 += 64) {
#pragma unroll
    for (int i = 0; i < MT + 4; i++) {
      const int c = wave * (MT + 4) + i;
      if (c < 4 * MT) {
        async_ld16(A + (size_t)(m0 + c * 8 + lrow) * K + kb + k0 + scol, As + c * 512);
      } else {
        const int cb = c - 4 * MT;
        async_ld16(BT + (size_t)(n0 + cb * 8 + lrow) * K + kb + k0 + scol,
                   Bs + cb * 512);
      }
    }
    __syncthreads();
#pragma unroll
    for (int ks = 0; ks < 64; ks += 32) {
      v8bf af[MT], bfr[4];
#pragma unroll
      for (int mt = 0; mt < MT; mt++)
        af[mt] = FRAG(As, wr + mt * 16 + l16, ks + quad * 8);
#pragma unroll
      for (int nt = 0; nt < 4; nt++)
        bfr[nt] = FRAG(Bs, wc + nt * 16 + l16, ks + quad * 8);
#pragma unroll
      for (int mt = 0; mt < MT; mt++)
#pragma unroll
        for (int nt = 0; nt < 4; nt++)
          acc[mt][nt] = __builtin_amdgcn_mfma_f32_16x16x32_bf16(
              af[mt], bfr[nt], acc[mt][nt], 0, 0, 0);
    }
    __syncthreads();
  }

#pragma unroll
  for (int mt = 0; mt < MT; mt++) {
#pragma unroll
    for (int r = 0; r < 4; r++) {
      const int gm = m0 + wr + mt * 16 + quad * 4 + r;
#pragma unroll
      for (int nt = 0; nt < 4; nt++) {
        const int gn = n0 + wc + nt * 16 + l16;
        float v = acc[mt][nt][r];
        if (MODE == 1) {
          outf[(size_t)gm * N + gn] = resid[(size_t)gm * N + gn] + v;
        } else {
          atomicAdd(&outf[(size_t)gm * N + gn], v);
        }
      }
    }
  }
}

// ---------------- GEMM 256x256 2-phase dbuf (plain HIP) --------------------
// C = A @ BT^T. A [M][K] bf16, BT [N][K] bf16. BM=BN=256, BK=64, 512 thr.
// 8 waves (2M x 4N); per-wave 128x64 output as STRIDED halves:
//   rows: mh*128 + wm*64 + (0..63)   cols: nh*128 + wn*32 + (0..31)
// Per K-tile: { stage tile t+1 into buf^1 | 24 FRAG ds_reads + 64 MFMA per
// wave from buf | __syncthreads }. R13-verified session-best structure.
// MODE 2: outb=bf16(gelu(C+bias))
// MODE 3: QKV mode — cols [0,2048) row-major bf16 into outb (N=3072 stride);
//         cols [2048,3072) transposed into vtg[(b*1024 + c)*2048 + t]
//         (c = gn-2048 = h*64+d). V cols are ONLY consumed via vtg.
template <int MODE, int PX, int PY>
__global__ __launch_bounds__(512, 2) void gemm256(
    const __hip_bfloat16* __restrict__ A,
    const __hip_bfloat16* __restrict__ BT,
    const float* __restrict__ bias,
    __hip_bfloat16* __restrict__ outb,
    __hip_bfloat16* __restrict__ vtg,
    int M, int N, int K, int Ksub)
{
  __shared__ __align__(16) __hip_bfloat16 As[2 * 256 * 64];  // 64 KiB
  __shared__ __align__(16) __hip_bfloat16 Bs[2 * 256 * 64];  // 64 KiB
  (void)M;
  const int tid = threadIdx.x;
  const int wave = tid >> 6, lane = tid & 63;
  const int quad = lane >> 4, l16 = lane & 15;
  const int wm = wave >> 2, wn = wave & 3;
  const int lrow = lane >> 3, scol = ((lane & 7) ^ lrow) * 8;

  int bx = blockIdx.x, by = blockIdx.y;
  {
    const int id = by * gridDim.x + bx;
    const int k = id & 7, s = id >> 3;
    const int pw = gridDim.x / PX, ph = gridDim.y / PY;
    bx = (k % PX) * pw + (s % pw);
    by = (k / PX) * ph + (s / pw);
  }
  const int m0 = by * 256, n0 = bx * 256;
  const size_t kb = 0;
  const int NT = Ksub >> 6;
  const int cg = wave * 2;  // this wave's 2 row-group slots (of 16 per half)

  auto stageA = [&](int h, int tt) {
#pragma unroll
    for (int j = 0; j < 2; j++) {
      const int rg = cg + j;
      async_ld16(A + (size_t)(m0 + h * 128 + rg * 8 + lrow) * K + kb + tt * 64 + scol,
                 As + ((tt & 1) * 16384 + (h * 128 + rg * 8) * 64));
    }
  };
  auto stageB = [&](int h, int tt) {
#pragma unroll
    for (int j = 0; j < 2; j++) {
      const int rg = cg + j;
      async_ld16(BT + (size_t)(n0 + h * 128 + rg * 8 + lrow) * K + kb + tt * 64 + scol,
                 Bs + ((tt & 1) * 16384 + (h * 128 + rg * 8) * 64));
    }
  };

  v4f acc[8][4];
#pragma unroll
  for (int i = 0; i < 8; i++)
#pragma unroll
    for (int j = 0; j < 4; j++)
#pragma unroll
      for (int c = 0; c < 4; c++) acc[i][j][c] = 0.0f;

  // prologue: stage tile 0, drain (implicit in __syncthreads)
  stageA(0, 0); stageB(0, 0); stageA(1, 0); stageB(1, 0);
  __syncthreads();

  for (int t = 0; t < NT; ++t) {
    if (t + 1 < NT) {
      stageA(0, t + 1); stageB(0, t + 1); stageA(1, t + 1); stageB(1, t + 1);
    }
    const __hip_bfloat16* Ab = As + (t & 1) * 16384;
    const __hip_bfloat16* Bb = Bs + (t & 1) * 16384;
#pragma unroll
    for (int ks = 0; ks < 2; ks++) {
      v8bf a[8], b[4];
#pragma unroll
      for (int mh = 0; mh < 2; mh++)
#pragma unroll
        for (int mt = 0; mt < 4; mt++)
          a[mh * 4 + mt] =
              FRAG(Ab, mh * 128 + wm * 64 + mt * 16 + l16, ks * 32 + quad * 8);
#pragma unroll
      for (int nh = 0; nh < 2; nh++)
#pragma unroll
        for (int nt = 0; nt < 2; nt++)
          b[nh * 2 + nt] =
              FRAG(Bb, nh * 128 + wn * 32 + nt * 16 + l16, ks * 32 + quad * 8);
#pragma unroll
      for (int mi = 0; mi < 8; mi++)
#pragma unroll
        for (int ni = 0; ni < 4; ni++)
          acc[mi][ni] = __builtin_amdgcn_mfma_f32_16x16x32_bf16(
              a[mi], b[ni], acc[mi][ni], 0, 0, 0);
    }
    if (t + 1 < NT) __syncthreads();
  }

  // epilogue: C/D layout col=lane&15, row=quad*4+reg
#pragma unroll
  for (int ni = 0; ni < 4; ni++) {
    const int gn = n0 + (ni >> 1) * 128 + wn * 32 + (ni & 1) * 16 + l16;
    float bcol = 0.0f;
    if (MODE == 2) bcol = bias[gn];
#pragma unroll
    for (int mi = 0; mi < 8; mi++) {
      const int gmb = m0 + (mi >> 2) * 128 + wm * 64 + (mi & 3) * 16 + quad * 4;
#pragma unroll
      for (int r = 0; r < 4; r++) {
        float v = acc[mi][ni][r];
        const int row = gmb + r;
        if (MODE == 2) {
          v += bcol;
          // tanh-GELU (max |err| ~1e-3 in h -> <1e-3 in final output)
          const float u = 0.7978845608f * (v + 0.044715f * v * v * v);
          const float e = EXP2F(u * 2.885390082f);  // exp(2u)
          const float th = 1.0f - 2.0f * __builtin_amdgcn_rcpf(e + 1.0f);
          v = 0.5f * v * (1.0f + th);
          outb[(size_t)row * N + gn] = __float2bfloat16(v);
        } else {  // MODE 3: QKV
          if (gn < 2048) {
            outb[(size_t)row * N + gn] = __float2bfloat16(v);
          } else {
            const int c = gn - 2048;               // h*64+d
            const int bb = row >> 11, tt = row & 2047;
            vtg[((size_t)(bb * 1024 + c)) * 2048 + tt] = __float2bfloat16(v);
          }
        }
      }
    }
  }
}

// ---------------- flash attention (causal, no-max exp2 softmax) ------------
__global__ __launch_bounds__(256, 2) void attn_kernel(
    const __hip_bfloat16* __restrict__ QKV,
    const __hip_bfloat16* __restrict__ VTg,
    __hip_bfloat16* __restrict__ Y)
{
  __shared__ __align__(16) __hip_bfloat16 Ks[2 * 64 * 64];
  __shared__ __align__(16) __hip_bfloat16 Vs[2 * 64 * 64];
  __shared__ __align__(16) __hip_bfloat16 PsA[64 * 64];
  __shared__ __align__(16) __hip_bfloat16 PsB[64 * 64];

  const int tid = threadIdx.x;
  const int wave = tid >> 6, lane = tid & 63;
  const int quad = lane >> 4, l16 = lane & 15;
  const int blk = blockIdx.x;
  const int p = blk & 15, h = (blk >> 4) & 15, b = blk >> 8;
  const int qa = p, qb = 31 - p, kmax = qb;
  const size_t rowbase = (size_t)b * T_SEQ;
  const size_t vbase = (size_t)(b * 16 + h) * 64;
  const int lrow = lane >> 3, scol = ((lane & 7) ^ (lane >> 3)) * 8;

  const float QSC = 0.125f * 1.44269504f;
  v8bf aqA[2], aqB[2];
#pragma unroll
  for (int ks = 0; ks < 2; ks++) {
    v8bf q = *(const v8bf*)(QKV + (rowbase + qa * 64 + wave * 16 + l16) * 3072 +
                            h * 64 + ks * 32 + quad * 8);
#pragma unroll
    for (int j = 0; j < 8; j++) aqA[ks][j] = (__bf16)((float)q[j] * QSC);
    q = *(const v8bf*)(QKV + (rowbase + qb * 64 + wave * 16 + l16) * 3072 +
                       h * 64 + ks * 32 + quad * 8);
#pragma unroll
    for (int j = 0; j < 8; j++) aqB[ks][j] = (__bf16)((float)q[j] * QSC);
  }

  v4f oA[4], oB[4];
  float lpA[4], lpB[4];
#pragma unroll
  for (int i = 0; i < 4; i++) {
    lpA[i] = 0.0f; lpB[i] = 0.0f;
#pragma unroll
    for (int c = 0; c < 4; c++) { oA[i][c] = 0.0f; oB[i][c] = 0.0f; }
  }

  auto stage = [&](int kt, int buf) {
#pragma unroll
    for (int i = 0; i < 2; i++) {
      const int r8 = i * 32 + wave * 8;
      const int rr = r8 + lrow;
      async_ld16(QKV + (rowbase + kt * 64 + rr) * 3072 + 1024 + h * 64 + scol,
                 Ks + buf * 4096 + r8 * 64);
      async_ld16(VTg + (vbase + rr) * T_SEQ + kt * 64 + scol,
                 Vs + buf * 4096 + r8 * 64);
    }
  };
  stage(0, 0);

  auto softmax_store = [&](v4f s[4], float lp[4], __hip_bfloat16* Ps, bool diag) {
    if (diag) {
#pragma unroll
      for (int nt = 0; nt < 4; nt++) {
        const int colr = nt * 16 + l16;
#pragma unroll
        for (int r = 0; r < 4; r++)
          if (colr > wave * 16 + quad * 4 + r) s[nt][r] = -30000.0f;
      }
    }
#pragma unroll
    for (int r = 0; r < 4; r++) {
      const int row = wave * 16 + quad * 4 + r;
      const int rsw = (quad * 4 + r) & 7;
#pragma unroll
      for (int nt = 0; nt < 4; nt++) {
        const float e = EXP2F(s[nt][r]);
        lp[r] += e;
        const int chunk = (nt * 2 + (l16 >> 3)) ^ rsw;
        Ps[row * 64 + (chunk << 3) + (l16 & 7)] = __float2bfloat16(e);
      }
    }
  };

  for (int kt = 0; kt <= kmax; kt++) {
    __syncthreads();
    if (kt < kmax) stage(kt + 1, (kt + 1) & 1);
    const __hip_bfloat16* Kb = Ks + (kt & 1) * 4096;
    const __hip_bfloat16* Vb = Vs + (kt & 1) * 4096;
    const bool doA = (kt <= qa);

    {
      v8bf kf[2][4];
#pragma unroll
      for (int ks = 0; ks < 2; ks++)
#pragma unroll
        for (int nt = 0; nt < 4; nt++)
          kf[ks][nt] = FRAG(Kb, nt * 16 + l16, ks * 32 + quad * 8);

      v4f sB[4];
#pragma unroll
      for (int nt = 0; nt < 4; nt++)
#pragma unroll
        for (int c = 0; c < 4; c++) sB[nt][c] = 0.0f;
      __builtin_amdgcn_s_setprio(1);
#pragma unroll
      for (int ks = 0; ks < 2; ks++)
#pragma unroll
        for (int nt = 0; nt < 4; nt++)
          sB[nt] = __builtin_amdgcn_mfma_f32_16x16x32_bf16(aqB[ks], kf[ks][nt],
                                                           sB[nt], 0, 0, 0);
      __builtin_amdgcn_s_setprio(0);
      softmax_store(sB, lpB, PsB, kt == qb);

      if (doA) {
        v4f sA[4];
#pragma unroll
        for (int nt = 0; nt < 4; nt++)
#pragma unroll
          for (int c = 0; c < 4; c++) sA[nt][c] = 0.0f;
        __builtin_amdgcn_s_setprio(1);
#pragma unroll
        for (int ks = 0; ks < 2; ks++)
#pragma unroll
          for (int nt = 0; nt < 4; nt++)
            sA[nt] = __builtin_amdgcn_mfma_f32_16x16x32_bf16(aqA[ks], kf[ks][nt],
                                                             sA[nt], 0, 0, 0);
        __builtin_amdgcn_s_setprio(0);
        softmax_store(sA, lpA, PsA, kt == qa);
      }
    }

    {
      v8bf vf[2][4];
#pragma unroll
      for (int ks = 0; ks < 2; ks++)
#pragma unroll
        for (int nt = 0; nt < 4; nt++)
          vf[ks][nt] = FRAG(Vb, nt * 16 + l16, ks * 32 + quad * 8);
      __builtin_amdgcn_s_setprio(1);
#pragma unroll
      for (int ks = 0; ks < 2; ks++) {
        const v8bf apB = FRAG(PsB, wave * 16 + l16, ks * 32 + quad * 8);
#pragma unroll
        for (int nt = 0; nt < 4; nt++)
          oB[nt] = __builtin_amdgcn_mfma_f32_16x16x32_bf16(apB, vf[ks][nt],
                                                           oB[nt], 0, 0, 0);
      }
      __builtin_amdgcn_s_setprio(0);
      if (doA) {
        __builtin_amdgcn_s_setprio(1);
#pragma unroll
        for (int ks = 0; ks < 2; ks++) {
          const v8bf apA = FRAG(PsA, wave * 16 + l16, ks * 32 + quad * 8);
#pragma unroll
          for (int nt = 0; nt < 4; nt++)
            oA[nt] = __builtin_amdgcn_mfma_f32_16x16x32_bf16(apA, vf[ks][nt],
                                                             oA[nt], 0, 0, 0);
        }
        __builtin_amdgcn_s_setprio(0);
      }
    }
  }

#pragma unroll
  for (int r = 0; r < 4; r++) {
    float la = lpA[r], lb = lpB[r];
#pragma unroll
    for (int off = 1; off < 16; off <<= 1) {
      la += __shfl_xor(la, off, 16);
      lb += __shfl_xor(lb, off, 16);
    }
    const float ila = 1.0f / la, ilb = 1.0f / lb;
#pragma unroll
    for (int nt = 0; nt < 4; nt++) {
      Y[(rowbase + qa * 64 + wave * 16 + quad * 4 + r) * 1024 + h * 64 + nt * 16 + l16] =
          __float2bfloat16(oA[nt][r] * ila);
      Y[(rowbase + qb * 64 + wave * 16 + quad * 4 + r) * 1024 + h * 64 + nt * 16 + l16] =
          __float2bfloat16(oB[nt][r] * ilb);
    }
  }
}

// ---------------------------------------------------------------------------
extern "C" void kernel_launch(void* const* d_in, const int* in_sizes, int n_in,
                              void* d_out, int out_size, void* d_ws, size_t ws_size,
                              hipStream_t stream)
{
  const float* x  = (const float*)d_in[0];
  const float* Wq = (const float*)d_in[1];
  const float* Wk = (const float*)d_in[2];
  const float* Wv = (const float*)d_in[3];
  const float* Wo = (const float*)d_in[4];
  const float* W1 = (const float*)d_in[5];
  const float* b1 = (const float*)d_in[6];
  const float* W2 = (const float*)d_in[7];
  const float* b2 = (const float*)d_in[8];
  const float* g1 = (const float*)d_in[9];
  const float* g2 = (const float*)d_in[10];

  uint8_t* ws = (uint8_t*)d_ws;
  __hip_bfloat16* WqkvT = (__hip_bfloat16*)(ws + 0);
  __hip_bfloat16* WoT   = (__hip_bfloat16*)(ws + 6291456);
  __hip_bfloat16* W1T   = (__hip_bfloat16*)(ws + 8388608);
  __hip_bfloat16* W2T   = (__hip_bfloat16*)(ws + 16777216);
  float*          x1    = (float*)(ws + 25165824);
  __hip_bfloat16* xn    = (__hip_bfloat16*)(ws + 41943040);
  __hip_bfloat16* Ybuf  = (__hip_bfloat16*)(ws + 41943040);
  __hip_bfloat16* QKV   = (__hip_bfloat16*)(ws + 50331648);
  __hip_bfloat16* VTg   = (__hip_bfloat16*)(ws + 75497472);
  __hip_bfloat16* Hbuf  = (__hip_bfloat16*)(ws + 50331648);

  const dim3 tb(32, 8);
  // prep: Wq/Wk/Wv/Wo + W1 + W2 transposes + rmsnorm1, one dispatch
  prep_kernel<<<16384, tb, 0, stream>>>(Wq, Wk, Wv, Wo, W1, W2,
                                        WqkvT, W1T, W2T, x, g1, xn);
  // QKV: 256^2 2-phase, grid (12,16); MODE 3 writes Q,K row-major and V
  // directly transposed into VTg (transpose_v eliminated)
  gemm256<3, 4, 2><<<dim3(12, 16), 512, 0, stream>>>(
      xn, WqkvT, nullptr, QKV, VTg, 4096, 3072, 1024, 1024);
  attn_kernel<<<512, 256, 0, stream>>>(QKV, VTg, Ybuf);
  // Wo: legacy structure (R13 best)
  gemm_bt<1, 2, 1, 8><<<dim3(8, 64), 256, 0, stream>>>(
      Ybuf, (const __hip_bfloat16*)(ws + 6291456), nullptr, x, nullptr, x1,
      4096, 1024, 1024, 1024);
  // rmsnorm2 also pre-initializes d_out = x1 + b2 (split-K atomic target)
  rmsnorm_kernel<<<4096, 256, 0, stream>>>(x1, g2, xn, b2, (float*)d_out);
  // FFN1: 256^2 2-phase, grid (16,16) = 256 blocks (1/CU); XCD patches 4x8
  gemm256<2, 4, 2><<<dim3(16, 16), 512, 0, stream>>>(
      xn, W1T, b1, Hbuf, nullptr, 4096, 4096, 1024, 1024);
  // FFN2: legacy split-K=2, MT=2 (R6/R8 best): 1024 blocks; atomics into d_out
  gemm_bt<4, 2, 1, 8><<<dim3(8, 64, 2), 256, 0, stream>>>(
      Hbuf, W2T, nullptr, nullptr, nullptr, (float*)d_out, 4096, 1024, 4096, 2048);
  (void)WoT;
}

// Round 9
// 322.023 us; speedup vs baseline: 1.0628x; 1.0628x over previous
//
#include <hip/hip_runtime.h>
#include <hip/hip_bf16.h>
#include <math.h>
#include <stdint.h>

// ---------------------------------------------------------------------------
// Transformer block: x + attn(rms(x,g1)) -> x1 ; x1 + ffn(rms(x1,g2))
// B=2 T=2048 D=1024 H=16 Dh=64 FF=4096. All GEMMs bf16 MFMA 16x16x32.
// R17: R13 base (session best 323.2us) + transpose_v fused into QKV gemm
//  CORRECTLY this time. R16's MODE-3 wrote VTg with per-element 2B stores at
//  4KB stride (uncoalesced -> QKV 47->65us). Fix: grid (12,16) makes every
//  block pure-QK (bx<8) or pure-V (bx>=8). Pure-V blocks transpose through
//  the (dead after K-loop) 128KB LDS: 2 passes of [128 c][256 t] tile with
//  chunk-XOR swizzle (p = t ^ ((c&7)<<3); chunk read at (j*8)^sw yields
//  t=j*8..j*8+7 in order), then 16B stores of 512B-contiguous VTg rows.
//  V row-major writes dropped (-8MB); transpose_v deleted (-1 dispatch,
//  -16MB). Prep kernels stay separate (R13 config; R14/R16 fusion unproven).
//  GEMM lessons final: counted-vmcnt defeated (R9-R11); MT=2 occupancy-first
//  loses B-traffic (R14); dbuf small tile loses occupancy/L2 (R15).
// LDS tiles use XOR-swizzled 16B chunks (chunk j of row r lives at j^(r&7));
// rocprof shows SQ_LDS_BANK_CONFLICT == 0 for this scheme.
// ---------------------------------------------------------------------------

typedef __bf16 v8bf  __attribute__((ext_vector_type(8)));
typedef float  v4f   __attribute__((ext_vector_type(4)));

#define T_SEQ 2048
#define EXP2F(x) __builtin_amdgcn_exp2f(x)  // v_exp_f32 (2^x)

// swizzled fragment read: row R, k-elem offset ko (multiple of 8)
#define FRAG(base, R, ko) \
  (*(const v8bf*)((base) + (R) * 64 + (((((ko) >> 3) ^ ((R) & 7))) << 3)))

__device__ __forceinline__ void async_ld16(const void* g, void* l) {
  // global -> LDS direct, 16B/lane. LDS dest is wave-uniform base + lane*16.
  __builtin_amdgcn_global_load_lds(
      (const __attribute__((address_space(1))) uint32_t*)g,
      (__attribute__((address_space(3))) uint32_t*)l, 16, 0, 0);
}

// ---------------- 4x weight transpose (Wq,Wk,Wv,Wo) fused ------------------
__global__ __launch_bounds__(256) void transpose_w4(
    const float* __restrict__ Wq, const float* __restrict__ Wk,
    const float* __restrict__ Wv, const float* __restrict__ Wo,
    __hip_bfloat16* __restrict__ out)
{
  __shared__ float tile[32][33];
  const int z = blockIdx.z;
  const float* W = z == 0 ? Wq : z == 1 ? Wk : z == 2 ? Wv : Wo;
  const int n0 = blockIdx.x * 32, k0 = blockIdx.y * 32;
  const int tx = threadIdx.x, ty = threadIdx.y;  // 32 x 8
#pragma unroll
  for (int i = 0; i < 32; i += 8)
    tile[ty + i][tx] = W[(size_t)(k0 + ty + i) * 1024 + n0 + tx];
  __syncthreads();
  __hip_bfloat16* o = out + (size_t)z * 1024 * 1024;
#pragma unroll
  for (int i = 0; i < 32; i += 8)
    o[(size_t)(n0 + ty + i) * 1024 + k0 + tx] = __float2bfloat16(tile[tx][ty + i]);
}

// ---------------- generic weight transpose ----------------------------------
__global__ __launch_bounds__(256) void transpose_w(
    const float* __restrict__ W, __hip_bfloat16* __restrict__ WT,
    int K, int N, int ldo)
{
  __shared__ float tile[32][33];
  const int n0 = blockIdx.x * 32, k0 = blockIdx.y * 32;
  const int tx = threadIdx.x, ty = threadIdx.y;  // 32 x 8
#pragma unroll
  for (int i = 0; i < 32; i += 8)
    tile[ty + i][tx] = W[(size_t)(k0 + ty + i) * N + n0 + tx];
  __syncthreads();
#pragma unroll
  for (int i = 0; i < 32; i += 8)
    WT[(size_t)(n0 + ty + i) * ldo + k0 + tx] = __float2bfloat16(tile[tx][ty + i]);
}

// ---------------- RMSNorm (fp32 in -> bf16 out, optional d_out init) -------
__global__ __launch_bounds__(256) void rmsnorm_kernel(
    const float* __restrict__ x, const float* __restrict__ g,
    __hip_bfloat16* __restrict__ out,
    const float* __restrict__ bias, float* __restrict__ dinit)
{
  const int row = blockIdx.x;
  const int t = threadIdx.x;
  const float4 v = ((const float4*)(x + (size_t)row * 1024))[t];
  float ss = v.x * v.x + v.y * v.y + v.z * v.z + v.w * v.w;
#pragma unroll
  for (int off = 32; off; off >>= 1) ss += __shfl_xor(ss, off, 64);
  __shared__ float red[4];
  if ((t & 63) == 0) red[t >> 6] = ss;
  __syncthreads();
  ss = red[0] + red[1] + red[2] + red[3];
  const float rs = rsqrtf(ss * (1.0f / 1024.0f) + 1e-6f);
  const float4 gv = ((const float4*)g)[t];
  __hip_bfloat16* o = out + (size_t)row * 1024 + t * 4;
  o[0] = __float2bfloat16(v.x * rs * gv.x);
  o[1] = __float2bfloat16(v.y * rs * gv.y);
  o[2] = __float2bfloat16(v.z * rs * gv.z);
  o[3] = __float2bfloat16(v.w * rs * gv.w);
  if (dinit) {
    const float4 bv = ((const float4*)bias)[t];
    float4 d;
    d.x = v.x + bv.x; d.y = v.y + bv.y; d.z = v.z + bv.z; d.w = v.w + bv.w;
    ((float4*)(dinit + (size_t)row * 1024))[t] = d;
  }
}

// ---------------- legacy GEMM (Wo, FFN2): C = A @ BT^T (+epilogue) ---------
// MODE 1: outf = resid + C   MODE 4: atomicAdd(outf, C)
template <int MODE, int MT, int PX, int PY>
__global__ __launch_bounds__(256, 2) void gemm_bt(
    const __hip_bfloat16* __restrict__ A,
    const __hip_bfloat16* __restrict__ BT,
    const float* __restrict__ bias,
    const float* __restrict__ resid,
    __hip_bfloat16* __restrict__ outb,
    float* __restrict__ outf,
    int M, int N, int K, int Ksub)
{
  __shared__ __align__(16) __hip_bfloat16 As[32 * MT * 64];
  __shared__ __align__(16) __hip_bfloat16 Bs[128 * 64];
  const int tid = threadIdx.x;
  const int wave = tid >> 6, lane = tid & 63;
  const int quad = lane >> 4, l16 = lane & 15;

  int bx = blockIdx.x, by = blockIdx.y;
  {
    const int id = by * gridDim.x + bx;
    const int k = id & 7, s = id >> 3;
    const int pw = gridDim.x / PX, ph = gridDim.y / PY;
    bx = (k % PX) * pw + (s % pw);
    by = (k / PX) * ph + (s / pw);
  }
  const int m0 = by * (32 * MT), n0 = bx * 128;
  const size_t kb = (size_t)blockIdx.z * Ksub;
  const int wr = (wave >> 1) * (16 * MT), wc = (wave & 1) * 64;
  const int lrow = lane >> 3;
  const int scol = ((lane & 7) ^ lrow) * 8;

  v4f acc[MT][4];
#pragma unroll
  for (int i = 0; i < MT; i++)
#pragma unroll
    for (int j = 0; j < 4; j++)
#pragma unroll
      for (int c = 0; c < 4; c++) acc[i][j][c] = 0.0f;

  for (int k0 = 0; k0 < Ksub; k0 += 64) {
#pragma unroll
    for (int i = 0; i < MT + 4; i++) {
      const int c = wave * (MT + 4) + i;
      if (c < 4 * MT) {
        async_ld16(A + (size_t)(m0 + c * 8 + lrow) * K + kb + k0 + scol, As + c * 512);
      } else {
        const int cb = c - 4 * MT;
        async_ld16(BT + (size_t)(n0 + cb * 8 + lrow) * K + kb + k0 + scol,
                   Bs + cb * 512);
      }
    }
    __syncthreads();
#pragma unroll
    for (int ks = 0; ks < 64; ks += 32) {
      v8bf af[MT], bfr[4];
#pragma unroll
      for (int mt = 0; mt < MT; mt++)
        af[mt] = FRAG(As, wr + mt * 16 + l16, ks + quad * 8);
#pragma unroll
      for (int nt = 0; nt < 4; nt++)
        bfr[nt] = FRAG(Bs, wc + nt * 16 + l16, ks + quad * 8);
#pragma unroll
      for (int mt = 0; mt < MT; mt++)
#pragma unroll
        for (int nt = 0; nt < 4; nt++)
          acc[mt][nt] = __builtin_amdgcn_mfma_f32_16x16x32_bf16(
              af[mt], bfr[nt], acc[mt][nt], 0, 0, 0);
    }
    __syncthreads();
  }

#pragma unroll
  for (int mt = 0; mt < MT; mt++) {
#pragma unroll
    for (int r = 0; r < 4; r++) {
      const int gm = m0 + wr + mt * 16 + quad * 4 + r;
#pragma unroll
      for (int nt = 0; nt < 4; nt++) {
        const int gn = n0 + wc + nt * 16 + l16;
        float v = acc[mt][nt][r];
        if (MODE == 1) {
          outf[(size_t)gm * N + gn] = resid[(size_t)gm * N + gn] + v;
        } else {
          atomicAdd(&outf[(size_t)gm * N + gn], v);
        }
      }
    }
  }
}

// ---------------- GEMM 256x256 2-phase dbuf (plain HIP) --------------------
// C = A @ BT^T. A [M][K] bf16, BT [N][K] bf16. BM=BN=256, BK=64, 512 thr.
// 8 waves (2M x 4N); per-wave 128x64 output as STRIDED halves:
//   rows: mh*128 + wm*64 + (0..63)   cols: nh*128 + wn*32 + (0..31)
// Per K-tile: { stage tile t+1 into buf^1 | 24 FRAG ds_reads + 64 MFMA per
// wave from buf | __syncthreads }. R13-verified session-best structure.
// MODE 2: outb=bf16(gelu(C+bias))
// MODE 3 (QKV): bx<8 -> Q/K cols row-major into outb (stride 3072).
//   bx>=8 -> pure-V block: transpose via LDS (As reused post-K-loop) into
//   vtg[(b*1024 + c)*2048 + t], 16B coalesced stores. V never written
//   row-major (only ever consumed transposed).
template <int MODE, int PX, int PY>
__global__ __launch_bounds__(512, 2) void gemm256(
    const __hip_bfloat16* __restrict__ A,
    const __hip_bfloat16* __restrict__ BT,
    const float* __restrict__ bias,
    __hip_bfloat16* __restrict__ outb,
    __hip_bfloat16* __restrict__ vtg,
    int M, int N, int K, int Ksub)
{
  __shared__ __align__(16) __hip_bfloat16 As[2 * 256 * 64];  // 64 KiB
  __shared__ __align__(16) __hip_bfloat16 Bs[2 * 256 * 64];  // 64 KiB
  (void)M;
  const int tid = threadIdx.x;
  const int wave = tid >> 6, lane = tid & 63;
  const int quad = lane >> 4, l16 = lane & 15;
  const int wm = wave >> 2, wn = wave & 3;
  const int lrow = lane >> 3, scol = ((lane & 7) ^ lrow) * 8;

  int bx = blockIdx.x, by = blockIdx.y;
  {
    const int id = by * gridDim.x + bx;
    const int k = id & 7, s = id >> 3;
    const int pw = gridDim.x / PX, ph = gridDim.y / PY;
    bx = (k % PX) * pw + (s % pw);
    by = (k / PX) * ph + (s / pw);
  }
  const int m0 = by * 256, n0 = bx * 256;
  const int NT = Ksub >> 6;
  const int cg = wave * 2;  // this wave's 2 row-group slots (of 16 per half)

  auto stageA = [&](int h, int tt) {
#pragma unroll
    for (int j = 0; j < 2; j++) {
      const int rg = cg + j;
      async_ld16(A + (size_t)(m0 + h * 128 + rg * 8 + lrow) * K + tt * 64 + scol,
                 As + ((tt & 1) * 16384 + (h * 128 + rg * 8) * 64));
    }
  };
  auto stageB = [&](int h, int tt) {
#pragma unroll
    for (int j = 0; j < 2; j++) {
      const int rg = cg + j;
      async_ld16(BT + (size_t)(n0 + h * 128 + rg * 8 + lrow) * K + tt * 64 + scol,
                 Bs + ((tt & 1) * 16384 + (h * 128 + rg * 8) * 64));
    }
  };

  v4f acc[8][4];
#pragma unroll
  for (int i = 0; i < 8; i++)
#pragma unroll
    for (int j = 0; j < 4; j++)
#pragma unroll
      for (int c = 0; c < 4; c++) acc[i][j][c] = 0.0f;

  // prologue: stage tile 0, drain (implicit in __syncthreads)
  stageA(0, 0); stageB(0, 0); stageA(1, 0); stageB(1, 0);
  __syncthreads();

  for (int t = 0; t < NT; ++t) {
    if (t + 1 < NT) {
      stageA(0, t + 1); stageB(0, t + 1); stageA(1, t + 1); stageB(1, t + 1);
    }
    const __hip_bfloat16* Ab = As + (t & 1) * 16384;
    const __hip_bfloat16* Bb = Bs + (t & 1) * 16384;
#pragma unroll
    for (int ks = 0; ks < 2; ks++) {
      v8bf a[8], b[4];
#pragma unroll
      for (int mh = 0; mh < 2; mh++)
#pragma unroll
        for (int mt = 0; mt < 4; mt++)
          a[mh * 4 + mt] =
              FRAG(Ab, mh * 128 + wm * 64 + mt * 16 + l16, ks * 32 + quad * 8);
#pragma unroll
      for (int nh = 0; nh < 2; nh++)
#pragma unroll
        for (int nt = 0; nt < 2; nt++)
          b[nh * 2 + nt] =
              FRAG(Bb, nh * 128 + wn * 32 + nt * 16 + l16, ks * 32 + quad * 8);
#pragma unroll
      for (int mi = 0; mi < 8; mi++)
#pragma unroll
        for (int ni = 0; ni < 4; ni++)
          acc[mi][ni] = __builtin_amdgcn_mfma_f32_16x16x32_bf16(
              a[mi], b[ni], acc[mi][ni], 0, 0, 0);
    }
    if (t + 1 < NT) __syncthreads();
  }

  if (MODE == 3 && n0 >= 2048) {
    // ---- pure-V block: LDS transpose -> coalesced VTg stores.
    // VTg[(b*1024 + c)*2048 + t]; c = gn-2048, block covers c0..c0+255,
    // t = m0..m0+255 (never straddles b: 2048 % 256 == 0).
    const int c0 = n0 - 2048;
    const int bb = m0 >> 11, t0 = m0 & 2047;
#pragma unroll
    for (int nh = 0; nh < 2; nh++) {
      __syncthreads();  // all waves done reading As (K-loop / prev pass)
      // scatter acc -> tile[128 c][256 t] at As; pos = t ^ ((c&7)<<3)
#pragma unroll
      for (int nt = 0; nt < 2; nt++) {
        const int cl = wn * 32 + nt * 16 + l16;
        const int sw = (cl & 7) << 3;
#pragma unroll
        for (int mi = 0; mi < 8; mi++) {
          const int tb = (mi >> 2) * 128 + wm * 64 + (mi & 3) * 16 + quad * 4;
#pragma unroll
          for (int r = 0; r < 4; r++)
            As[cl * 256 + ((tb + r) ^ sw)] =
                __float2bfloat16(acc[mi][nh * 2 + nt][r]);
        }
      }
      __syncthreads();
      // coalesced store: chunk at offset (j*8)^sw holds t = j*8..j*8+7
#pragma unroll
      for (int it = 0; it < 8; ++it) {
        const int cl = it * 16 + (tid >> 5);
        const int j = tid & 31;
        const int sw = (cl & 7) << 3;
        const v8bf vv = *(const v8bf*)(As + cl * 256 + ((j * 8) ^ sw));
        *(v8bf*)(vtg + ((size_t)(bb * 1024 + c0 + nh * 128 + cl)) * 2048 +
                 t0 + j * 8) = vv;
      }
    }
    return;
  }

  // epilogue: C/D layout col=lane&15, row=quad*4+reg
#pragma unroll
  for (int ni = 0; ni < 4; ni++) {
    const int gn = n0 + (ni >> 1) * 128 + wn * 32 + (ni & 1) * 16 + l16;
    float bcol = 0.0f;
    if (MODE == 2) bcol = bias[gn];
#pragma unroll
    for (int mi = 0; mi < 8; mi++) {
      const int gmb = m0 + (mi >> 2) * 128 + wm * 64 + (mi & 3) * 16 + quad * 4;
#pragma unroll
      for (int r = 0; r < 4; r++) {
        float v = acc[mi][ni][r];
        const size_t idx = (size_t)(gmb + r) * N + gn;
        if (MODE == 3) {
          outb[idx] = __float2bfloat16(v);  // pure Q/K block (gn < 2048)
        } else {
          v += bcol;
          // tanh-GELU (max |err| ~1e-3 in h -> <1e-3 in final output)
          const float u = 0.7978845608f * (v + 0.044715f * v * v * v);
          const float e = EXP2F(u * 2.885390082f);  // exp(2u)
          const float th = 1.0f - 2.0f * __builtin_amdgcn_rcpf(e + 1.0f);
          v = 0.5f * v * (1.0f + th);
          outb[idx] = __float2bfloat16(v);
        }
      }
    }
  }
}

// ---------------- flash attention (causal, no-max exp2 softmax) ------------
__global__ __launch_bounds__(256, 2) void attn_kernel(
    const __hip_bfloat16* __restrict__ QKV,
    const __hip_bfloat16* __restrict__ VTg,
    __hip_bfloat16* __restrict__ Y)
{
  __shared__ __align__(16) __hip_bfloat16 Ks[2 * 64 * 64];
  __shared__ __align__(16) __hip_bfloat16 Vs[2 * 64 * 64];
  __shared__ __align__(16) __hip_bfloat16 PsA[64 * 64];
  __shared__ __align__(16) __hip_bfloat16 PsB[64 * 64];

  const int tid = threadIdx.x;
  const int wave = tid >> 6, lane = tid & 63;
  const int quad = lane >> 4, l16 = lane & 15;
  const int blk = blockIdx.x;
  const int p = blk & 15, h = (blk >> 4) & 15, b = blk >> 8;
  const int qa = p, qb = 31 - p, kmax = qb;
  const size_t rowbase = (size_t)b * T_SEQ;
  const size_t vbase = (size_t)(b * 16 + h) * 64;
  const int lrow = lane >> 3, scol = ((lane & 7) ^ (lane >> 3)) * 8;

  const float QSC = 0.125f * 1.44269504f;
  v8bf aqA[2], aqB[2];
#pragma unroll
  for (int ks = 0; ks < 2; ks++) {
    v8bf q = *(const v8bf*)(QKV + (rowbase + qa * 64 + wave * 16 + l16) * 3072 +
                            h * 64 + ks * 32 + quad * 8);
#pragma unroll
    for (int j = 0; j < 8; j++) aqA[ks][j] = (__bf16)((float)q[j] * QSC);
    q = *(const v8bf*)(QKV + (rowbase + qb * 64 + wave * 16 + l16) * 3072 +
                       h * 64 + ks * 32 + quad * 8);
#pragma unroll
    for (int j = 0; j < 8; j++) aqB[ks][j] = (__bf16)((float)q[j] * QSC);
  }

  v4f oA[4], oB[4];
  float lpA[4], lpB[4];
#pragma unroll
  for (int i = 0; i < 4; i++) {
    lpA[i] = 0.0f; lpB[i] = 0.0f;
#pragma unroll
    for (int c = 0; c < 4; c++) { oA[i][c] = 0.0f; oB[i][c] = 0.0f; }
  }

  auto stage = [&](int kt, int buf) {
#pragma unroll
    for (int i = 0; i < 2; i++) {
      const int r8 = i * 32 + wave * 8;
      const int rr = r8 + lrow;
      async_ld16(QKV + (rowbase + kt * 64 + rr) * 3072 + 1024 + h * 64 + scol,
                 Ks + buf * 4096 + r8 * 64);
      async_ld16(VTg + (vbase + rr) * T_SEQ + kt * 64 + scol,
                 Vs + buf * 4096 + r8 * 64);
    }
  };
  stage(0, 0);

  auto softmax_store = [&](v4f s[4], float lp[4], __hip_bfloat16* Ps, bool diag) {
    if (diag) {
#pragma unroll
      for (int nt = 0; nt < 4; nt++) {
        const int colr = nt * 16 + l16;
#pragma unroll
        for (int r = 0; r < 4; r++)
          if (colr > wave * 16 + quad * 4 + r) s[nt][r] = -30000.0f;
      }
    }
#pragma unroll
    for (int r = 0; r < 4; r++) {
      const int row = wave * 16 + quad * 4 + r;
      const int rsw = (quad * 4 + r) & 7;
#pragma unroll
      for (int nt = 0; nt < 4; nt++) {
        const float e = EXP2F(s[nt][r]);
        lp[r] += e;
        const int chunk = (nt * 2 + (l16 >> 3)) ^ rsw;
        Ps[row * 64 + (chunk << 3) + (l16 & 7)] = __float2bfloat16(e);
      }
    }
  };

  for (int kt = 0; kt <= kmax; kt++) {
    __syncthreads();
    if (kt < kmax) stage(kt + 1, (kt + 1) & 1);
    const __hip_bfloat16* Kb = Ks + (kt & 1) * 4096;
    const __hip_bfloat16* Vb = Vs + (kt & 1) * 4096;
    const bool doA = (kt <= qa);

    {
      v8bf kf[2][4];
#pragma unroll
      for (int ks = 0; ks < 2; ks++)
#pragma unroll
        for (int nt = 0; nt < 4; nt++)
          kf[ks][nt] = FRAG(Kb, nt * 16 + l16, ks * 32 + quad * 8);

      v4f sB[4];
#pragma unroll
      for (int nt = 0; nt < 4; nt++)
#pragma unroll
        for (int c = 0; c < 4; c++) sB[nt][c] = 0.0f;
      __builtin_amdgcn_s_setprio(1);
#pragma unroll
      for (int ks = 0; ks < 2; ks++)
#pragma unroll
        for (int nt = 0; nt < 4; nt++)
          sB[nt] = __builtin_amdgcn_mfma_f32_16x16x32_bf16(aqB[ks], kf[ks][nt],
                                                           sB[nt], 0, 0, 0);
      __builtin_amdgcn_s_setprio(0);
      softmax_store(sB, lpB, PsB, kt == qb);

      if (doA) {
        v4f sA[4];
#pragma unroll
        for (int nt = 0; nt < 4; nt++)
#pragma unroll
          for (int c = 0; c < 4; c++) sA[nt][c] = 0.0f;
        __builtin_amdgcn_s_setprio(1);
#pragma unroll
        for (int ks = 0; ks < 2; ks++)
#pragma unroll
          for (int nt = 0; nt < 4; nt++)
            sA[nt] = __builtin_amdgcn_mfma_f32_16x16x32_bf16(aqA[ks], kf[ks][nt],
                                                             sA[nt], 0, 0, 0);
        __builtin_amdgcn_s_setprio(0);
        softmax_store(sA, lpA, PsA, kt == qa);
      }
    }

    {
      v8bf vf[2][4];
#pragma unroll
      for (int ks = 0; ks < 2; ks++)
#pragma unroll
        for (int nt = 0; nt < 4; nt++)
          vf[ks][nt] = FRAG(Vb, nt * 16 + l16, ks * 32 + quad * 8);
      __builtin_amdgcn_s_setprio(1);
#pragma unroll
      for (int ks = 0; ks < 2; ks++) {
        const v8bf apB = FRAG(PsB, wave * 16 + l16, ks * 32 + quad * 8);
#pragma unroll
        for (int nt = 0; nt < 4; nt++)
          oB[nt] = __builtin_amdgcn_mfma_f32_16x16x32_bf16(apB, vf[ks][nt],
                                                           oB[nt], 0, 0, 0);
      }
      __builtin_amdgcn_s_setprio(0);
      if (doA) {
        __builtin_amdgcn_s_setprio(1);
#pragma unroll
        for (int ks = 0; ks < 2; ks++) {
          const v8bf apA = FRAG(PsA, wave * 16 + l16, ks * 32 + quad * 8);
#pragma unroll
          for (int nt = 0; nt < 4; nt++)
            oA[nt] = __builtin_amdgcn_mfma_f32_16x16x32_bf16(apA, vf[ks][nt],
                                                             oA[nt], 0, 0, 0);
        }
        __builtin_amdgcn_s_setprio(0);
      }
    }
  }

#pragma unroll
  for (int r = 0; r < 4; r++) {
    float la = lpA[r], lb = lpB[r];
#pragma unroll
    for (int off = 1; off < 16; off <<= 1) {
      la += __shfl_xor(la, off, 16);
      lb += __shfl_xor(lb, off, 16);
    }
    const float ila = 1.0f / la, ilb = 1.0f / lb;
#pragma unroll
    for (int nt = 0; nt < 4; nt++) {
      Y[(rowbase + qa * 64 + wave * 16 + quad * 4 + r) * 1024 + h * 64 + nt * 16 + l16] =
          __float2bfloat16(oA[nt][r] * ila);
      Y[(rowbase + qb * 64 + wave * 16 + quad * 4 + r) * 1024 + h * 64 + nt * 16 + l16] =
          __float2bfloat16(oB[nt][r] * ilb);
    }
  }
}

// ---------------------------------------------------------------------------
extern "C" void kernel_launch(void* const* d_in, const int* in_sizes, int n_in,
                              void* d_out, int out_size, void* d_ws, size_t ws_size,
                              hipStream_t stream)
{
  const float* x  = (const float*)d_in[0];
  const float* Wq = (const float*)d_in[1];
  const float* Wk = (const float*)d_in[2];
  const float* Wv = (const float*)d_in[3];
  const float* Wo = (const float*)d_in[4];
  const float* W1 = (const float*)d_in[5];
  const float* b1 = (const float*)d_in[6];
  const float* W2 = (const float*)d_in[7];
  const float* b2 = (const float*)d_in[8];
  const float* g1 = (const float*)d_in[9];
  const float* g2 = (const float*)d_in[10];

  uint8_t* ws = (uint8_t*)d_ws;
  __hip_bfloat16* WqkvT = (__hip_bfloat16*)(ws + 0);
  __hip_bfloat16* WoT   = (__hip_bfloat16*)(ws + 6291456);
  __hip_bfloat16* W1T   = (__hip_bfloat16*)(ws + 8388608);
  __hip_bfloat16* W2T   = (__hip_bfloat16*)(ws + 16777216);
  float*          x1    = (float*)(ws + 25165824);
  __hip_bfloat16* xn    = (__hip_bfloat16*)(ws + 41943040);
  __hip_bfloat16* Ybuf  = (__hip_bfloat16*)(ws + 41943040);
  __hip_bfloat16* QKV   = (__hip_bfloat16*)(ws + 50331648);
  __hip_bfloat16* VTg   = (__hip_bfloat16*)(ws + 75497472);
  __hip_bfloat16* Hbuf  = (__hip_bfloat16*)(ws + 50331648);

  const dim3 tb(32, 8);
  transpose_w4<<<dim3(32, 32, 4), tb, 0, stream>>>(Wq, Wk, Wv, Wo, WqkvT);
  transpose_w<<<dim3(128, 32), tb, 0, stream>>>(W1, W1T, 1024, 4096, 1024);
  transpose_w<<<dim3(32, 128), tb, 0, stream>>>(W2, W2T, 4096, 1024, 4096);

  rmsnorm_kernel<<<4096, 256, 0, stream>>>(x, g1, xn, nullptr, nullptr);
  // QKV: 256^2 2-phase, grid (12,16); MODE 3: Q/K row-major, V transposed
  // through LDS into VTg with coalesced 16B stores (transpose_v eliminated)
  gemm256<3, 4, 2><<<dim3(12, 16), 512, 0, stream>>>(
      xn, WqkvT, nullptr, QKV, VTg, 4096, 3072, 1024, 1024);
  attn_kernel<<<512, 256, 0, stream>>>(QKV, VTg, Ybuf);
  // Wo: legacy structure (R13 best)
  gemm_bt<1, 2, 1, 8><<<dim3(8, 64), 256, 0, stream>>>(
      Ybuf, WoT, nullptr, x, nullptr, x1, 4096, 1024, 1024, 1024);
  // rmsnorm2 also pre-initializes d_out = x1 + b2 (split-K atomic target)
  rmsnorm_kernel<<<4096, 256, 0, stream>>>(x1, g2, xn, b2, (float*)d_out);
  // FFN1: 256^2 2-phase, grid (16,16) = 256 blocks (1/CU); XCD patches 4x8
  gemm256<2, 4, 2><<<dim3(16, 16), 512, 0, stream>>>(
      xn, W1T, b1, Hbuf, nullptr, 4096, 4096, 1024, 1024);
  // FFN2: legacy split-K=2, MT=2 (R6/R8 best): 1024 blocks; atomics into d_out
  gemm_bt<4, 2, 1, 8><<<dim3(8, 64, 2), 256, 0, stream>>>(
      Hbuf, W2T, nullptr, nullptr, nullptr, (float*)d_out, 4096, 1024, 4096, 2048);
}